// Round 10
// baseline (386.147 us; speedup 1.0000x reference)
//
#include <hip/hip_runtime.h>

#define BATCH 4
#define SEQ   2048
#define DMODEL 1024
#define NHEADS 16
#define HDIM  64
#define MROWS (BATCH * SEQ)   // 8192

typedef float f32x4 __attribute__((ext_vector_type(4)));
typedef short s16x8 __attribute__((ext_vector_type(8)));
typedef short s16x4 __attribute__((ext_vector_type(4)));
typedef unsigned short u16;

#define MFMA32K(a, b, c) __builtin_amdgcn_mfma_f32_16x16x32_bf16((a), (b), (c), 0, 0, 0)
#define MFMA16K(a, b, c) __builtin_amdgcn_mfma_f32_16x16x16bf16_1k((a), (b), (c), 0, 0, 0)

__device__ __forceinline__ u16 f2bf(float x) {
    unsigned int u = __builtin_bit_cast(unsigned int, x);
    unsigned int r = u + 0x7fffu + ((u >> 16) & 1u);
    return (u16)(r >> 16);
}

#if __has_builtin(__builtin_amdgcn_cvt_pk_bf16_f32)
__device__ __forceinline__ unsigned int pack2bf(float a, float b) {
    auto r = __builtin_amdgcn_cvt_pk_bf16_f32(a, b);  // 1 VALU op
    return __builtin_bit_cast(unsigned int, r);
}
#else
__device__ __forceinline__ unsigned int pack2bf(float a, float b) {
    return (unsigned int)f2bf(a) | ((unsigned int)f2bf(b) << 16);
}
#endif

// async global->LDS DMA, 16B/lane; LDS dest = wave-uniform base + lane*16
__device__ __forceinline__ void dma16(const u16* g, const u16* l) {
    __builtin_amdgcn_global_load_lds(
        (const __attribute__((address_space(1))) unsigned int*)g,
        (__attribute__((address_space(3))) unsigned int*)l, 16, 0, 0);
}

// ---------------------------------------------------------------------------
// Fused prep: blocks [0,12288) = fp32->bf16 convert of q/k/v (8 elem/thread);
// blocks [12288,13312) = W[k][n] fp32 -> Wt[n][k] bf16 64x64 tile transpose.
// ---------------------------------------------------------------------------
__global__ __launch_bounds__(256) void prep(
    const float* __restrict__ s0, const float* __restrict__ s1,
    const float* __restrict__ s2, u16* __restrict__ d0, u16* __restrict__ d1,
    u16* __restrict__ d2, const float* __restrict__ W0,
    const float* __restrict__ W1, const float* __restrict__ W2,
    const float* __restrict__ W3, u16* __restrict__ Wt) {
    __shared__ u16 tile[64][80];
    const int bid = blockIdx.x;
    const int t = threadIdx.x;
    if (bid < 12288) {
        // ---- convk3 path ----
        const int z = bid >> 12, xi = bid & 4095;
        const float* src = (z == 0) ? s0 : (z == 1) ? s1 : s2;
        u16* dst = (z == 0) ? d0 : (z == 1) ? d1 : d2;
        const int i = xi * 256 + t;
        float4 a = ((const float4*)src)[i * 2];
        float4 b = ((const float4*)src)[i * 2 + 1];
        uint4 o;
        o.x = pack2bf(a.x, a.y); o.y = pack2bf(a.z, a.w);
        o.z = pack2bf(b.x, b.y); o.w = pack2bf(b.z, b.w);
        *(uint4*)(dst + (size_t)i * 8) = o;
    } else {
        // ---- wconv path ----
        const int wb = bid - 12288;
        const int mtx = wb >> 8;
        const int rem = wb & 255;
        const float* W = (mtx == 0) ? W0 : (mtx == 1) ? W1 : (mtx == 2) ? W2 : W3;
        u16* out = Wt + (size_t)mtx * DMODEL * DMODEL;
        const int n0 = (rem & 15) * 64, k0 = (rem >> 4) * 64;
#pragma unroll
        for (int j = 0; j < 4; ++j) {
            int k = j * 16 + (t >> 4);
            int c = (t & 15) * 4;
            float4 v = *(const float4*)(W + (size_t)(k0 + k) * DMODEL + n0 + c);
            tile[c + 0][k] = f2bf(v.x);
            tile[c + 1][k] = f2bf(v.y);
            tile[c + 2][k] = f2bf(v.z);
            tile[c + 3][k] = f2bf(v.w);
        }
        __syncthreads();
#pragma unroll
        for (int i2 = 0; i2 < 2; ++i2) {
            int n = i2 * 32 + (t >> 3), ck = (t & 7) * 8;
            uint4 v = *(const uint4*)(&tile[n][ck]);
            *(uint4*)(out + (size_t)(n0 + n) * DMODEL + k0 + ck) = v;
        }
    }
}

// ---------------------------------------------------------------------------
// Fused QKV GEMM, all-bf16, BK=64 + XOR-unit-swizzled LDS.
// v11: BM 128 -> 256 (acc[8][4], waves 2x2 each owning 128x64). Bytes/FLOP
// -25% (B-panel amortized over 2x rows), barriers per FLOP halved -- the
// same more-compute-per-stage lever that won for attn QBLK=256. LDS 48KB,
// VGPR ~210 -> 2 blocks/CU. Grid (32 m, 8 n, 3 z), m-fast for L2 locality.
// ---------------------------------------------------------------------------
__global__ __launch_bounds__(256) void gemm_qkv(
    const u16* __restrict__ Aq, const u16* __restrict__ Ak,
    const u16* __restrict__ Av, const u16* __restrict__ Wt,
    const float* __restrict__ biq, const float* __restrict__ bik,
    const float* __restrict__ biv, u16* __restrict__ oq, u16* __restrict__ ok,
    u16* __restrict__ ov, float sq) {
    __shared__ u16 As[256 * 64];
    __shared__ u16 Bs[128 * 64];
    const int t = threadIdx.x;
    const int w = t >> 6, lane = t & 63, quad = lane >> 4, l16 = lane & 15;
    const int z = blockIdx.z;
    const u16* A = (z == 0) ? Aq : (z == 1) ? Ak : Av;
    const u16* B = Wt + (size_t)z * DMODEL * DMODEL;
    const float* bias = (z == 0) ? biq : (z == 1) ? bik : biv;
    u16* C = (z == 0) ? oq : (z == 1) ? ok : ov;
    const float scale = (z == 0) ? sq : 1.0f;
    const int m0 = blockIdx.x * 256, n0 = blockIdx.y * 128;
    const int wm = (w >> 1) * 128, wn = (w & 1) * 64;
    const int lr8 = lane >> 3;                 // row within 8-row issue group
    const int lun = (lane & 7) ^ lr8;          // pre-swizzled source unit

    f32x4 acc[8][4] = {};

    for (int k0 = 0; k0 < DMODEL; k0 += 64) {
#pragma unroll
        for (int j = 0; j < 8; ++j) {          // A: 256 rows
            int r8 = j * 32 + w * 8;
            dma16(A + (size_t)(m0 + r8 + lr8) * DMODEL + k0 + lun * 8, &As[r8 * 64]);
        }
#pragma unroll
        for (int j = 0; j < 4; ++j) {          // B: 128 rows
            int r8 = j * 32 + w * 8;
            dma16(B + (size_t)(n0 + r8 + lr8) * DMODEL + k0 + lun * 8, &Bs[r8 * 64]);
        }
        __syncthreads();
#pragma unroll
        for (int half = 0; half < 2; ++half) {
            s16x8 af[8], bf[4];
#pragma unroll
            for (int mt = 0; mt < 8; ++mt) {
                int un = ((half * 4 + quad) ^ (l16 & 7)) * 8;
                af[mt] = *(const s16x8*)(&As[(wm + mt * 16 + l16) * 64 + un]);
            }
#pragma unroll
            for (int nt = 0; nt < 4; ++nt) {
                int un = ((half * 4 + quad) ^ (l16 & 7)) * 8;
                bf[nt] = *(const s16x8*)(&Bs[(wn + nt * 16 + l16) * 64 + un]);
            }
#pragma unroll
            for (int mt = 0; mt < 8; ++mt)
#pragma unroll
                for (int nt = 0; nt < 4; ++nt)
                    acc[mt][nt] = MFMA32K(af[mt], bf[nt], acc[mt][nt]);
        }
        __syncthreads();
    }

#pragma unroll
    for (int mt = 0; mt < 8; ++mt)
#pragma unroll
        for (int nt = 0; nt < 4; ++nt) {
            int col = n0 + wn + nt * 16 + l16;
            float bv_ = bias[col];
#pragma unroll
            for (int r = 0; r < 4; ++r) {
                int row = m0 + wm + mt * 16 + quad * 4 + r;
                C[(size_t)row * DMODEL + col] = f2bf((acc[mt][nt][r] + bv_) * scale);
            }
        }
}

// ---------------------------------------------------------------------------
// Output projection GEMM: same BM=256 BK=64 swizzled structure, fp32 out.
// Grid (32 m, 8 n), m-fast.
// ---------------------------------------------------------------------------
__global__ __launch_bounds__(256) void gemm_o(const u16* __restrict__ A,
                                              const u16* __restrict__ Bt,
                                              const float* __restrict__ bias,
                                              float* __restrict__ Cp) {
    __shared__ u16 As[256 * 64];
    __shared__ u16 Bs[128 * 64];
    const int t = threadIdx.x;
    const int w = t >> 6, lane = t & 63, quad = lane >> 4, l16 = lane & 15;
    const int m0 = blockIdx.x * 256, n0 = blockIdx.y * 128;
    const int wm = (w >> 1) * 128, wn = (w & 1) * 64;
    const int lr8 = lane >> 3;
    const int lun = (lane & 7) ^ lr8;

    f32x4 acc[8][4] = {};

    for (int k0 = 0; k0 < DMODEL; k0 += 64) {
#pragma unroll
        for (int j = 0; j < 8; ++j) {
            int r8 = j * 32 + w * 8;
            dma16(A + (size_t)(m0 + r8 + lr8) * DMODEL + k0 + lun * 8, &As[r8 * 64]);
        }
#pragma unroll
        for (int j = 0; j < 4; ++j) {
            int r8 = j * 32 + w * 8;
            dma16(Bt + (size_t)(n0 + r8 + lr8) * DMODEL + k0 + lun * 8, &Bs[r8 * 64]);
        }
        __syncthreads();
#pragma unroll
        for (int half = 0; half < 2; ++half) {
            s16x8 af[8], bf[4];
#pragma unroll
            for (int mt = 0; mt < 8; ++mt) {
                int un = ((half * 4 + quad) ^ (l16 & 7)) * 8;
                af[mt] = *(const s16x8*)(&As[(wm + mt * 16 + l16) * 64 + un]);
            }
#pragma unroll
            for (int nt = 0; nt < 4; ++nt) {
                int un = ((half * 4 + quad) ^ (l16 & 7)) * 8;
                bf[nt] = *(const s16x8*)(&Bs[(wn + nt * 16 + l16) * 64 + un]);
            }
#pragma unroll
            for (int mt = 0; mt < 8; ++mt)
#pragma unroll
                for (int nt = 0; nt < 4; ++nt)
                    acc[mt][nt] = MFMA32K(af[mt], bf[nt], acc[mt][nt]);
        }
        __syncthreads();
    }

#pragma unroll
    for (int mt = 0; mt < 8; ++mt)
#pragma unroll
        for (int nt = 0; nt < 4; ++nt) {
            int col = n0 + wn + nt * 16 + l16;
            float bv_ = bias[col];
#pragma unroll
            for (int r = 0; r < 4; ++r) {
                int row = m0 + wm + mt * 16 + quad * 4 + r;
                Cp[(size_t)row * DMODEL + col] = acc[mt][nt][r] + bv_;
            }
        }
}

// ---------------------------------------------------------------------------
// Flash attention, S^T formulation, fixed m=0. Grid (head, q-block, b),
// head-fast: all 8 q-blocks of one (b,h) KV stream land on the same XCD.
// v9 exactly (PMC 117.4us, best measured): QBLK=256, round-0 two-barrier
// schedule, shfl row-sum (ones-row variant measured worse: +MFMA > -VALU).
// ---------------------------------------------------------------------------
__global__ __launch_bounds__(256, 2) void attn3(const u16* __restrict__ qb,
                                                const u16* __restrict__ kb,
                                                const u16* __restrict__ vb,
                                                u16* __restrict__ ctxb) {
    __shared__ u16 Ks[64 * 64];  // [key][swizzled 16B units], stride 64
    __shared__ u16 Vt[64 * 72];  // [dim][swizzled key], stride 72
    const int t = threadIdx.x;
    const int w = t >> 6, lane = t & 63, quad = lane >> 4, l16 = lane & 15;
    const int h = blockIdx.x, b = blockIdx.z, q0 = blockIdx.y * 256;

    // Q B-fragments (pre-scaled by 0.125*log2e in projection epilogue)
    // wave w owns q-rows [q0 + w*64, q0 + w*64 + 64)
    s16x8 bq[4][2];
#pragma unroll
    for (int qs = 0; qs < 4; ++qs) {
        size_t base = (size_t)(b * SEQ + q0 + w * 64 + qs * 16 + l16) * DMODEL + h * HDIM + quad * 8;
        bq[qs][0] = *(const s16x8*)(qb + base);
        bq[qs][1] = *(const s16x8*)(qb + base + 32);
    }

    const int krow = lane >> 3;
    const int kunit = (lane & 7) ^ (krow & 7);

    float lsum[4] = {0.0f, 0.0f, 0.0f, 0.0f};
    f32x4 o[4][4] = {};

    for (int s0 = 0; s0 < SEQ; s0 += 64) {
        __syncthreads();
        // ---- K via dma16 (swizzled): Ks[row][unit ^ (row&7)] ----
#pragma unroll
        for (int j = 0; j < 2; ++j) {
            int row = w * 16 + j * 8 + krow;
            dma16(kb + (size_t)(b * SEQ + s0 + row) * DMODEL + h * HDIM + kunit * 8,
                  &Ks[(w * 16 + j * 8) * 64]);
        }
        // ---- V transposed + swizzled (manual) ----
#pragma unroll
        for (int i = 0; i < 2; ++i) {
            int idx = i * 256 + t;
            int key = idx >> 3, seg = idx & 7;
            union { uint4 v; u16 s[8]; } u;
            u.v = *(const uint4*)(vb + (size_t)(b * SEQ + s0 + key) * DMODEL + h * HDIM + seg * 8);
            int col = (((key >> 3) ^ seg) << 3) + (key & 7);
#pragma unroll
            for (int ii = 0; ii < 8; ++ii)
                Vt[(seg * 8 + ii) * 72 + col] = u.s[ii];
        }
        __syncthreads();

        // ---- K A-fragments (swizzled units: 2-way, free) ----
        s16x8 ak[4][2];
#pragma unroll
        for (int kt = 0; kt < 4; ++kt) {
            int row = kt * 16 + l16;
#pragma unroll
            for (int hf = 0; hf < 2; ++hf) {
                int un = (hf * 4 + quad) ^ (l16 & 7);
                ak[kt][hf] = *(const s16x8*)(&Ks[row * 64 + un * 8]);
            }
        }

        // ---- scores + softmax (m=0 fixed), P packed in regs, 4 q-strips ----
        unsigned int pk[4][4][2];
#pragma unroll
        for (int qs = 0; qs < 4; ++qs) {
            f32x4 sc[4];
#pragma unroll
            for (int kt = 0; kt < 4; ++kt) {
                f32x4 zz = {0.0f, 0.0f, 0.0f, 0.0f};
                zz = MFMA32K(ak[kt][0], bq[qs][0], zz);
                sc[kt] = MFMA32K(ak[kt][1], bq[qs][1], zz);
            }
            float rs = 0.0f;
            float p[4][4];
#pragma unroll
            for (int kt = 0; kt < 4; ++kt)
#pragma unroll
                for (int r = 0; r < 4; ++r) {
                    p[kt][r] = __builtin_amdgcn_exp2f(sc[kt][r]);
                    rs += p[kt][r];
                }
            rs += __shfl_xor(rs, 16);
            rs += __shfl_xor(rs, 32);
            lsum[qs] += rs;
#pragma unroll
            for (int kt = 0; kt < 4; ++kt) {
                pk[qs][kt][0] = pack2bf(p[kt][0], p[kt][1]);
                pk[qs][kt][1] = pack2bf(p[kt][2], p[kt][3]);
            }
        }

        // ---- PV: O^T += V^T . P^T (av reused across 4 q-strips) ----
#pragma unroll
        for (int mt = 0; mt < 4; ++mt) {
            const int dim = mt * 16 + l16;
            const int swz = (dim >> 3) & 7;
            const int rowoff = dim * 72;
#pragma unroll
            for (int kt = 0; kt < 4; ++kt) {
                int col = ((((kt * 2) + (quad >> 1)) ^ swz) << 3) + ((quad & 1) << 2);
                s16x4 av = *(const s16x4*)(&Vt[rowoff + col]);
#pragma unroll
                for (int qs = 0; qs < 4; ++qs) {
                    union { unsigned int u[2]; s16x4 v; } pb;
                    pb.u[0] = pk[qs][kt][0];
                    pb.u[1] = pk[qs][kt][1];
                    o[qs][mt] = MFMA16K(av, pb.v, o[qs][mt]);
                }
            }
        }
    }

    // ---- epilogue: O^T[dim][qrow] / l -> ctx (bf16, dword stores) ----
#pragma unroll
    for (int qs = 0; qs < 4; ++qs) {
        float rl = 1.0f / lsum[qs];
        size_t rowbase = (size_t)(b * SEQ + q0 + w * 64 + qs * 16 + l16) * DMODEL + h * HDIM;
#pragma unroll
        for (int mt = 0; mt < 4; ++mt)
#pragma unroll
            for (int rr = 0; rr < 2; ++rr) {
                unsigned int v = pack2bf(o[qs][mt][rr * 2] * rl, o[qs][mt][rr * 2 + 1] * rl);
                *(unsigned int*)(&ctxb[rowbase + mt * 16 + quad * 4 + rr * 2]) = v;
            }
    }
}

// ---------------------------------------------------------------------------
extern "C" void kernel_launch(void* const* d_in, const int* in_sizes, int n_in,
                              void* d_out, int out_size, void* d_ws, size_t ws_size,
                              hipStream_t stream) {
    const float* queries = (const float*)d_in[0];
    const float* keys    = (const float*)d_in[1];
    const float* values  = (const float*)d_in[2];
    const float* Wq = (const float*)d_in[3];
    const float* bq = (const float*)d_in[4];
    const float* Wk = (const float*)d_in[5];
    const float* bk = (const float*)d_in[6];
    const float* Wv = (const float*)d_in[7];
    const float* bv = (const float*)d_in[8];
    const float* Wo = (const float*)d_in[9];
    const float* bo = (const float*)d_in[10];
    float* out = (float*)d_out;

    // workspace layout (104 MB total)
    char* ws = (char*)d_ws;
    u16* Wt   = (u16*)ws;                           // 8 MB  (4 x 1024^2 bf16)
    u16* aq   = (u16*)(ws + ((size_t)8 << 20));     // 16 MB bf16 queries
    u16* ak   = (u16*)(ws + ((size_t)24 << 20));    // 16 MB bf16 keys
    u16* av   = (u16*)(ws + ((size_t)40 << 20));    // 16 MB bf16 values
    u16* qbuf = (u16*)(ws + ((size_t)56 << 20));    // 16 MB
    u16* kbuf = (u16*)(ws + ((size_t)72 << 20));    // 16 MB
    u16* vbuf = (u16*)(ws + ((size_t)88 << 20));    // 16 MB
    u16* ctxb = qbuf;  // alias: attn block rewrites only the rows it read

    const size_t WSZ = (size_t)DMODEL * DMODEL;
    const float S2 = 0.125f * 1.44269504088896340736f;  // 1/sqrt(64) * log2(e)

    dim3 blk(256);

    prep<<<dim3(13312), blk, 0, stream>>>(queries, keys, values, aq, ak, av,
                                          Wq, Wk, Wv, Wo, Wt);

    gemm_qkv<<<dim3(32, 8, 3), blk, 0, stream>>>(aq, ak, av, Wt,
                                                 bq, bk, bv, qbuf, kbuf, vbuf, S2);

    attn3<<<dim3(NHEADS, SEQ / 256, BATCH), blk, 0, stream>>>(qbuf, kbuf, vbuf, ctxb);

    gemm_o<<<dim3(32, 8), blk, 0, stream>>>(ctxb, Wt + 3 * WSZ, bo, out);
}

// Round 12
// 351.543 us; speedup vs baseline: 1.0984x; 1.0984x over previous
//
#include <hip/hip_runtime.h>

#define BATCH 4
#define SEQ   2048
#define DMODEL 1024
#define NHEADS 16
#define HDIM  64
#define MROWS (BATCH * SEQ)   // 8192

typedef float f32x4 __attribute__((ext_vector_type(4)));
typedef short s16x8 __attribute__((ext_vector_type(8)));
typedef short s16x4 __attribute__((ext_vector_type(4)));
typedef unsigned short u16;

#define MFMA32K(a, b, c) __builtin_amdgcn_mfma_f32_16x16x32_bf16((a), (b), (c), 0, 0, 0)
#define MFMA16K(a, b, c) __builtin_amdgcn_mfma_f32_16x16x16bf16_1k((a), (b), (c), 0, 0, 0)

__device__ __forceinline__ u16 f2bf(float x) {
    unsigned int u = __builtin_bit_cast(unsigned int, x);
    unsigned int r = u + 0x7fffu + ((u >> 16) & 1u);
    return (u16)(r >> 16);
}

#if __has_builtin(__builtin_amdgcn_cvt_pk_bf16_f32)
__device__ __forceinline__ unsigned int pack2bf(float a, float b) {
    auto r = __builtin_amdgcn_cvt_pk_bf16_f32(a, b);  // 1 VALU op
    return __builtin_bit_cast(unsigned int, r);
}
#else
__device__ __forceinline__ unsigned int pack2bf(float a, float b) {
    return (unsigned int)f2bf(a) | ((unsigned int)f2bf(b) << 16);
}
#endif

// async global->LDS DMA, 16B/lane; LDS dest = wave-uniform base + lane*16
__device__ __forceinline__ void dma16(const u16* g, const u16* l) {
    __builtin_amdgcn_global_load_lds(
        (const __attribute__((address_space(1))) unsigned int*)g,
        (__attribute__((address_space(3))) unsigned int*)l, 16, 0, 0);
}

// ---------------------------------------------------------------------------
// Fused prep: blocks [0,12288) = fp32->bf16 convert of q/k/v (8 elem/thread);
// blocks [12288,13312) = W[k][n] fp32 -> Wt[n][k] bf16 64x64 tile transpose.
// ---------------------------------------------------------------------------
__global__ __launch_bounds__(256) void prep(
    const float* __restrict__ s0, const float* __restrict__ s1,
    const float* __restrict__ s2, u16* __restrict__ d0, u16* __restrict__ d1,
    u16* __restrict__ d2, const float* __restrict__ W0,
    const float* __restrict__ W1, const float* __restrict__ W2,
    const float* __restrict__ W3, u16* __restrict__ Wt) {
    __shared__ u16 tile[64][80];
    const int bid = blockIdx.x;
    const int t = threadIdx.x;
    if (bid < 12288) {
        // ---- convk3 path ----
        const int z = bid >> 12, xi = bid & 4095;
        const float* src = (z == 0) ? s0 : (z == 1) ? s1 : s2;
        u16* dst = (z == 0) ? d0 : (z == 1) ? d1 : d2;
        const int i = xi * 256 + t;
        float4 a = ((const float4*)src)[i * 2];
        float4 b = ((const float4*)src)[i * 2 + 1];
        uint4 o;
        o.x = pack2bf(a.x, a.y); o.y = pack2bf(a.z, a.w);
        o.z = pack2bf(b.x, b.y); o.w = pack2bf(b.z, b.w);
        *(uint4*)(dst + (size_t)i * 8) = o;
    } else {
        // ---- wconv path ----
        const int wb = bid - 12288;
        const int mtx = wb >> 8;
        const int rem = wb & 255;
        const float* W = (mtx == 0) ? W0 : (mtx == 1) ? W1 : (mtx == 2) ? W2 : W3;
        u16* out = Wt + (size_t)mtx * DMODEL * DMODEL;
        const int n0 = (rem & 15) * 64, k0 = (rem >> 4) * 64;
#pragma unroll
        for (int j = 0; j < 4; ++j) {
            int k = j * 16 + (t >> 4);
            int c = (t & 15) * 4;
            float4 v = *(const float4*)(W + (size_t)(k0 + k) * DMODEL + n0 + c);
            tile[c + 0][k] = f2bf(v.x);
            tile[c + 1][k] = f2bf(v.y);
            tile[c + 2][k] = f2bf(v.z);
            tile[c + 3][k] = f2bf(v.w);
        }
        __syncthreads();
#pragma unroll
        for (int i2 = 0; i2 < 2; ++i2) {
            int n = i2 * 32 + (t >> 3), ck = (t & 7) * 8;
            uint4 v = *(const uint4*)(&tile[n][ck]);
            *(uint4*)(out + (size_t)(n0 + n) * DMODEL + k0 + ck) = v;
        }
    }
}

// ---------------------------------------------------------------------------
// Fused QKV GEMM, all-bf16, BK=64 + XOR-unit-swizzled LDS (proven round 6).
// BM=128: 4 blocks/CU -- the TLP that hides the 2-barrier stage (BM=256
// at 2 blocks/CU measured worse). Grid (64 m, 8 n, 3 z), m-fast: A-strip
// stays L2-resident on its XCD.
// ---------------------------------------------------------------------------
__global__ __launch_bounds__(256) void gemm_qkv(
    const u16* __restrict__ Aq, const u16* __restrict__ Ak,
    const u16* __restrict__ Av, const u16* __restrict__ Wt,
    const float* __restrict__ biq, const float* __restrict__ bik,
    const float* __restrict__ biv, u16* __restrict__ oq, u16* __restrict__ ok,
    u16* __restrict__ ov, float sq) {
    __shared__ u16 As[128 * 64];
    __shared__ u16 Bs[128 * 64];
    const int t = threadIdx.x;
    const int w = t >> 6, lane = t & 63, quad = lane >> 4, l16 = lane & 15;
    const int z = blockIdx.z;
    const u16* A = (z == 0) ? Aq : (z == 1) ? Ak : Av;
    const u16* B = Wt + (size_t)z * DMODEL * DMODEL;
    const float* bias = (z == 0) ? biq : (z == 1) ? bik : biv;
    u16* C = (z == 0) ? oq : (z == 1) ? ok : ov;
    const float scale = (z == 0) ? sq : 1.0f;
    const int m0 = blockIdx.x * 128, n0 = blockIdx.y * 128;
    const int wm = (w >> 1) * 64, wn = (w & 1) * 64;
    const int lr8 = lane >> 3;                 // row within 8-row issue group
    const int lun = (lane & 7) ^ lr8;          // pre-swizzled source unit

    f32x4 acc[4][4] = {};

    for (int k0 = 0; k0 < DMODEL; k0 += 64) {
#pragma unroll
        for (int j = 0; j < 4; ++j) {
            int r8 = w * 32 + j * 8;           // issue-group base row
            dma16(A + (size_t)(m0 + r8 + lr8) * DMODEL + k0 + lun * 8, &As[r8 * 64]);
            dma16(B + (size_t)(n0 + r8 + lr8) * DMODEL + k0 + lun * 8, &Bs[r8 * 64]);
        }
        __syncthreads();
#pragma unroll
        for (int half = 0; half < 2; ++half) {
            s16x8 af[4], bf[4];
#pragma unroll
            for (int mt = 0; mt < 4; ++mt) {
                int un = ((half * 4 + quad) ^ (l16 & 7)) * 8;
                af[mt] = *(const s16x8*)(&As[(wm + mt * 16 + l16) * 64 + un]);
                bf[mt] = *(const s16x8*)(&Bs[(wn + mt * 16 + l16) * 64 + un]);
            }
#pragma unroll
            for (int mt = 0; mt < 4; ++mt)
#pragma unroll
                for (int nt = 0; nt < 4; ++nt)
                    acc[mt][nt] = MFMA32K(af[mt], bf[nt], acc[mt][nt]);
        }
        __syncthreads();
    }

#pragma unroll
    for (int mt = 0; mt < 4; ++mt)
#pragma unroll
        for (int nt = 0; nt < 4; ++nt) {
            int col = n0 + wn + nt * 16 + l16;
            float bv_ = bias[col];
#pragma unroll
            for (int r = 0; r < 4; ++r) {
                int row = m0 + wm + mt * 16 + quad * 4 + r;
                C[(size_t)row * DMODEL + col] = f2bf((acc[mt][nt][r] + bv_) * scale);
            }
        }
}

// ---------------------------------------------------------------------------
// Output projection GEMM: same BK=64 swizzled structure, fp32 out.
// ---------------------------------------------------------------------------
__global__ __launch_bounds__(256) void gemm_o(const u16* __restrict__ A,
                                              const u16* __restrict__ Bt,
                                              const float* __restrict__ bias,
                                              float* __restrict__ Cp) {
    __shared__ u16 As[128 * 64];
    __shared__ u16 Bs[128 * 64];
    const int t = threadIdx.x;
    const int w = t >> 6, lane = t & 63, quad = lane >> 4, l16 = lane & 15;
    const int m0 = blockIdx.x * 128, n0 = blockIdx.y * 128;
    const int wm = (w >> 1) * 64, wn = (w & 1) * 64;
    const int lr8 = lane >> 3;
    const int lun = (lane & 7) ^ lr8;

    f32x4 acc[4][4] = {};

    for (int k0 = 0; k0 < DMODEL; k0 += 64) {
#pragma unroll
        for (int j = 0; j < 4; ++j) {
            int r8 = w * 32 + j * 8;
            dma16(A + (size_t)(m0 + r8 + lr8) * DMODEL + k0 + lun * 8, &As[r8 * 64]);
            dma16(Bt + (size_t)(n0 + r8 + lr8) * DMODEL + k0 + lun * 8, &Bs[r8 * 64]);
        }
        __syncthreads();
#pragma unroll
        for (int half = 0; half < 2; ++half) {
            s16x8 af[4], bf[4];
#pragma unroll
            for (int mt = 0; mt < 4; ++mt) {
                int un = ((half * 4 + quad) ^ (l16 & 7)) * 8;
                af[mt] = *(const s16x8*)(&As[(wm + mt * 16 + l16) * 64 + un]);
                bf[mt] = *(const s16x8*)(&Bs[(wn + mt * 16 + l16) * 64 + un]);
            }
#pragma unroll
            for (int mt = 0; mt < 4; ++mt)
#pragma unroll
                for (int nt = 0; nt < 4; ++nt)
                    acc[mt][nt] = MFMA32K(af[mt], bf[nt], acc[mt][nt]);
        }
        __syncthreads();
    }

#pragma unroll
    for (int mt = 0; mt < 4; ++mt)
#pragma unroll
        for (int nt = 0; nt < 4; ++nt) {
            int col = n0 + wn + nt * 16 + l16;
            float bv_ = bias[col];
#pragma unroll
            for (int r = 0; r < 4; ++r) {
                int row = m0 + wm + mt * 16 + quad * 4 + r;
                Cp[(size_t)row * DMODEL + col] = acc[mt][nt][r] + bv_;
            }
        }
}

// ---------------------------------------------------------------------------
// Flash attention, S^T formulation, fixed m=0. Grid (head, q-block, b),
// head-fast: all 8 q-blocks of one (b,h) KV stream land on the same XCD.
//
// v10 (round-9 best total): QBLK=256 + ones-row lsum. Vt has 80 rows; row 64
// = 1.0 bf16 (uniform -> swizzle-invariant), rows 65-79 = 0, written once.
// PV mt loop runs to 5; o[qs][4][0] accumulates sum_k P on the MFMA pipe.
// Epilogue broadcasts the sum via one __shfl per qs.
// ---------------------------------------------------------------------------
__global__ __launch_bounds__(256, 2) void attn3(const u16* __restrict__ qb,
                                                const u16* __restrict__ kb,
                                                const u16* __restrict__ vb,
                                                u16* __restrict__ ctxb) {
    __shared__ u16 Ks[64 * 64];  // [key][swizzled 16B units], stride 64
    __shared__ u16 Vt[80 * 72];  // [dim 0..63 + ones-row 64][swizzled key]
    const int t = threadIdx.x;
    const int w = t >> 6, lane = t & 63, quad = lane >> 4, l16 = lane & 15;
    const int h = blockIdx.x, b = blockIdx.z, q0 = blockIdx.y * 256;

    // Q B-fragments (pre-scaled by 0.125*log2e in projection epilogue)
    // wave w owns q-rows [q0 + w*64, q0 + w*64 + 64)
    s16x8 bq[4][2];
#pragma unroll
    for (int qs = 0; qs < 4; ++qs) {
        size_t base = (size_t)(b * SEQ + q0 + w * 64 + qs * 16 + l16) * DMODEL + h * HDIM + quad * 8;
        bq[qs][0] = *(const s16x8*)(qb + base);
        bq[qs][1] = *(const s16x8*)(qb + base + 32);
    }

    // ones-row block init (rows 64..79): row 64 = 1.0 bf16, rest 0. Once.
    for (int idx = t; idx < 16 * 72; idx += 256) {
        int r = idx / 72, c = idx - r * 72;
        Vt[(64 + r) * 72 + c] = (r == 0) ? (u16)0x3F80 : (u16)0;
    }

    const int krow = lane >> 3;
    const int kunit = (lane & 7) ^ (krow & 7);

    f32x4 o[4][5] = {};  // [qs][mt]; mt=4 is the P-sum row

    for (int s0 = 0; s0 < SEQ; s0 += 64) {
        __syncthreads();
        // ---- K via dma16 (swizzled): Ks[row][unit ^ (row&7)] ----
#pragma unroll
        for (int j = 0; j < 2; ++j) {
            int row = w * 16 + j * 8 + krow;
            dma16(kb + (size_t)(b * SEQ + s0 + row) * DMODEL + h * HDIM + kunit * 8,
                  &Ks[(w * 16 + j * 8) * 64]);
        }
        // ---- V transposed + swizzled (manual) ----
#pragma unroll
        for (int i = 0; i < 2; ++i) {
            int idx = i * 256 + t;
            int key = idx >> 3, seg = idx & 7;
            union { uint4 v; u16 s[8]; } u;
            u.v = *(const uint4*)(vb + (size_t)(b * SEQ + s0 + key) * DMODEL + h * HDIM + seg * 8);
            int col = (((key >> 3) ^ seg) << 3) + (key & 7);
#pragma unroll
            for (int ii = 0; ii < 8; ++ii)
                Vt[(seg * 8 + ii) * 72 + col] = u.s[ii];
        }
        __syncthreads();

        // ---- K A-fragments (swizzled units: 2-way, free) ----
        s16x8 ak[4][2];
#pragma unroll
        for (int kt = 0; kt < 4; ++kt) {
            int row = kt * 16 + l16;
#pragma unroll
            for (int hf = 0; hf < 2; ++hf) {
                int un = (hf * 4 + quad) ^ (l16 & 7);
                ak[kt][hf] = *(const s16x8*)(&Ks[row * 64 + un * 8]);
            }
        }

        // ---- scores + softmax (m=0 fixed), P packed in regs, 4 q-strips ----
        unsigned int pk[4][4][2];
#pragma unroll
        for (int qs = 0; qs < 4; ++qs) {
            f32x4 sc[4];
#pragma unroll
            for (int kt = 0; kt < 4; ++kt) {
                f32x4 zz = {0.0f, 0.0f, 0.0f, 0.0f};
                zz = MFMA32K(ak[kt][0], bq[qs][0], zz);
                sc[kt] = MFMA32K(ak[kt][1], bq[qs][1], zz);
            }
#pragma unroll
            for (int kt = 0; kt < 4; ++kt) {
                float p0 = __builtin_amdgcn_exp2f(sc[kt][0]);
                float p1 = __builtin_amdgcn_exp2f(sc[kt][1]);
                float p2 = __builtin_amdgcn_exp2f(sc[kt][2]);
                float p3 = __builtin_amdgcn_exp2f(sc[kt][3]);
                pk[qs][kt][0] = pack2bf(p0, p1);
                pk[qs][kt][1] = pack2bf(p2, p3);
            }
        }

        // ---- PV: O^T += V^T . P^T; mt=4 accumulates sum_k P (ones-row) ----
#pragma unroll
        for (int mt = 0; mt < 5; ++mt) {
            const int dim = mt * 16 + l16;
            const int swz = (dim >> 3) & 7;
            const int rowoff = dim * 72;
#pragma unroll
            for (int kt = 0; kt < 4; ++kt) {
                int col = ((((kt * 2) + (quad >> 1)) ^ swz) << 3) + ((quad & 1) << 2);
                s16x4 av = *(const s16x4*)(&Vt[rowoff + col]);
#pragma unroll
                for (int qs = 0; qs < 4; ++qs) {
                    union { unsigned int u[2]; s16x4 v; } pb;
                    pb.u[0] = pk[qs][kt][0];
                    pb.u[1] = pk[qs][kt][1];
                    o[qs][mt] = MFMA16K(av, pb.v, o[qs][mt]);
                }
            }
        }
    }

    // ---- epilogue: O^T[dim][qrow] / lsum -> ctx (bf16, dword stores) ----
    // lsum for q=l16 lives in o[qs][4][0] at quad-0 lanes; broadcast via shfl.
#pragma unroll
    for (int qs = 0; qs < 4; ++qs) {
        float ls = __shfl(o[qs][4][0], l16);
        float rl = 1.0f / ls;
        size_t rowbase = (size_t)(b * SEQ + q0 + w * 64 + qs * 16 + l16) * DMODEL + h * HDIM;
#pragma unroll
        for (int mt = 0; mt < 4; ++mt)
#pragma unroll
            for (int rr = 0; rr < 2; ++rr) {
                unsigned int v = pack2bf(o[qs][mt][rr * 2] * rl, o[qs][mt][rr * 2 + 1] * rl);
                *(unsigned int*)(&ctxb[rowbase + mt * 16 + quad * 4 + rr * 2]) = v;
            }
    }
}

// ---------------------------------------------------------------------------
extern "C" void kernel_launch(void* const* d_in, const int* in_sizes, int n_in,
                              void* d_out, int out_size, void* d_ws, size_t ws_size,
                              hipStream_t stream) {
    const float* queries = (const float*)d_in[0];
    const float* keys    = (const float*)d_in[1];
    const float* values  = (const float*)d_in[2];
    const float* Wq = (const float*)d_in[3];
    const float* bq = (const float*)d_in[4];
    const float* Wk = (const float*)d_in[5];
    const float* bk = (const float*)d_in[6];
    const float* Wv = (const float*)d_in[7];
    const float* bv = (const float*)d_in[8];
    const float* Wo = (const float*)d_in[9];
    const float* bo = (const float*)d_in[10];
    float* out = (float*)d_out;

    // workspace layout (104 MB total)
    char* ws = (char*)d_ws;
    u16* Wt   = (u16*)ws;                           // 8 MB  (4 x 1024^2 bf16)
    u16* aq   = (u16*)(ws + ((size_t)8 << 20));     // 16 MB bf16 queries
    u16* ak   = (u16*)(ws + ((size_t)24 << 20));    // 16 MB bf16 keys
    u16* av   = (u16*)(ws + ((size_t)40 << 20));    // 16 MB bf16 values
    u16* qbuf = (u16*)(ws + ((size_t)56 << 20));    // 16 MB
    u16* kbuf = (u16*)(ws + ((size_t)72 << 20));    // 16 MB
    u16* vbuf = (u16*)(ws + ((size_t)88 << 20));    // 16 MB
    u16* ctxb = qbuf;  // alias: attn block rewrites only the rows it read

    const size_t WSZ = (size_t)DMODEL * DMODEL;
    const float S2 = 0.125f * 1.44269504088896340736f;  // 1/sqrt(64) * log2(e)

    dim3 blk(256);

    prep<<<dim3(13312), blk, 0, stream>>>(queries, keys, values, aq, ak, av,
                                          Wq, Wk, Wv, Wo, Wt);

    gemm_qkv<<<dim3(64, 8, 3), blk, 0, stream>>>(aq, ak, av, Wt,
                                                 bq, bk, bv, qbuf, kbuf, vbuf, S2);

    attn3<<<dim3(NHEADS, SEQ / 256, BATCH), blk, 0, stream>>>(qbuf, kbuf, vbuf, ctxb);

    gemm_o<<<dim3(64, 8), blk, 0, stream>>>(ctxb, Wt + 3 * WSZ, bo, out);
}

// Round 14
// 342.679 us; speedup vs baseline: 1.1268x; 1.0259x over previous
//
#include <hip/hip_runtime.h>

#define BATCH 4
#define SEQ   2048
#define DMODEL 1024
#define NHEADS 16
#define HDIM  64
#define MROWS (BATCH * SEQ)   // 8192

typedef float f32x4 __attribute__((ext_vector_type(4)));
typedef short s16x8 __attribute__((ext_vector_type(8)));
typedef short s16x4 __attribute__((ext_vector_type(4)));
typedef unsigned short u16;

#define MFMA32K(a, b, c) __builtin_amdgcn_mfma_f32_16x16x32_bf16((a), (b), (c), 0, 0, 0)
#define MFMA16K(a, b, c) __builtin_amdgcn_mfma_f32_16x16x16bf16_1k((a), (b), (c), 0, 0, 0)

__device__ __forceinline__ u16 f2bf(float x) {
    unsigned int u = __builtin_bit_cast(unsigned int, x);
    unsigned int r = u + 0x7fffu + ((u >> 16) & 1u);
    return (u16)(r >> 16);
}

#if __has_builtin(__builtin_amdgcn_cvt_pk_bf16_f32)
__device__ __forceinline__ unsigned int pack2bf(float a, float b) {
    auto r = __builtin_amdgcn_cvt_pk_bf16_f32(a, b);  // 1 VALU op
    return __builtin_bit_cast(unsigned int, r);
}
#else
__device__ __forceinline__ unsigned int pack2bf(float a, float b) {
    return (unsigned int)f2bf(a) | ((unsigned int)f2bf(b) << 16);
}
#endif

// async global->LDS DMA, 16B/lane; LDS dest = wave-uniform base + lane*16
__device__ __forceinline__ void dma16(const u16* g, const u16* l) {
    __builtin_amdgcn_global_load_lds(
        (const __attribute__((address_space(1))) unsigned int*)g,
        (__attribute__((address_space(3))) unsigned int*)l, 16, 0, 0);
}

// ---------------------------------------------------------------------------
// Fused prep: blocks [0,12288) = fp32->bf16 convert of q/k/v (8 elem/thread);
// blocks [12288,13312) = W[k][n] fp32 -> Wt[n][k] bf16 64x64 tile transpose.
// ---------------------------------------------------------------------------
__global__ __launch_bounds__(256) void prep(
    const float* __restrict__ s0, const float* __restrict__ s1,
    const float* __restrict__ s2, u16* __restrict__ d0, u16* __restrict__ d1,
    u16* __restrict__ d2, const float* __restrict__ W0,
    const float* __restrict__ W1, const float* __restrict__ W2,
    const float* __restrict__ W3, u16* __restrict__ Wt) {
    __shared__ u16 tile[64][80];
    const int bid = blockIdx.x;
    const int t = threadIdx.x;
    if (bid < 12288) {
        // ---- convk3 path ----
        const int z = bid >> 12, xi = bid & 4095;
        const float* src = (z == 0) ? s0 : (z == 1) ? s1 : s2;
        u16* dst = (z == 0) ? d0 : (z == 1) ? d1 : d2;
        const int i = xi * 256 + t;
        float4 a = ((const float4*)src)[i * 2];
        float4 b = ((const float4*)src)[i * 2 + 1];
        uint4 o;
        o.x = pack2bf(a.x, a.y); o.y = pack2bf(a.z, a.w);
        o.z = pack2bf(b.x, b.y); o.w = pack2bf(b.z, b.w);
        *(uint4*)(dst + (size_t)i * 8) = o;
    } else {
        // ---- wconv path ----
        const int wb = bid - 12288;
        const int mtx = wb >> 8;
        const int rem = wb & 255;
        const float* W = (mtx == 0) ? W0 : (mtx == 1) ? W1 : (mtx == 2) ? W2 : W3;
        u16* out = Wt + (size_t)mtx * DMODEL * DMODEL;
        const int n0 = (rem & 15) * 64, k0 = (rem >> 4) * 64;
#pragma unroll
        for (int j = 0; j < 4; ++j) {
            int k = j * 16 + (t >> 4);
            int c = (t & 15) * 4;
            float4 v = *(const float4*)(W + (size_t)(k0 + k) * DMODEL + n0 + c);
            tile[c + 0][k] = f2bf(v.x);
            tile[c + 1][k] = f2bf(v.y);
            tile[c + 2][k] = f2bf(v.z);
            tile[c + 3][k] = f2bf(v.w);
        }
        __syncthreads();
#pragma unroll
        for (int i2 = 0; i2 < 2; ++i2) {
            int n = i2 * 32 + (t >> 3), ck = (t & 7) * 8;
            uint4 v = *(const uint4*)(&tile[n][ck]);
            *(uint4*)(out + (size_t)(n0 + n) * DMODEL + k0 + ck) = v;
        }
    }
}

// ---------------------------------------------------------------------------
// Fused QKV GEMM, all-bf16. v14 = v13 counted-vmcnt pipeline with the race
// fixed: raw __builtin s_barrier is NOT a compiler memory fence, so v13's
// ds_reads could hoist above the barrier (reading LDS before OTHER waves'
// DMA landed -> absmax 9.6e-3). Barrier is now asm volatile("s_barrier")
// with "memory" clobber + sched_barrier(0): no memory op crosses it.
// HW protocol (unchanged, sound): STAGE(next) -> vmcnt(4) waits only the
// PREVIOUS tile's 4 loads (a full compute phase to land) -> s_barrier ->
// all waves' DMA for the computed buffer is chip-visible -> ds_read+MFMA.
// BK=32, static dbuf (32 KB LDS -> 4 blocks/CU). 4-unit XOR swizzle:
// LDS slot s of row r holds source unit s^(r&3); read slot quad^(l16&3).
// Grid (64 m, 8 n, 3 z), m-fast.
// ---------------------------------------------------------------------------
__global__ __launch_bounds__(256) void gemm_qkv(
    const u16* __restrict__ Aq, const u16* __restrict__ Ak,
    const u16* __restrict__ Av, const u16* __restrict__ Wt,
    const float* __restrict__ biq, const float* __restrict__ bik,
    const float* __restrict__ biv, u16* __restrict__ oq, u16* __restrict__ ok,
    u16* __restrict__ ov, float sq) {
    __shared__ u16 As0[128 * 32];
    __shared__ u16 Bs0[128 * 32];
    __shared__ u16 As1[128 * 32];
    __shared__ u16 Bs1[128 * 32];
    const int t = threadIdx.x;
    const int w = t >> 6, lane = t & 63, quad = lane >> 4, l16 = lane & 15;
    const int z = blockIdx.z;
    const u16* A = (z == 0) ? Aq : (z == 1) ? Ak : Av;
    const u16* B = Wt + (size_t)z * DMODEL * DMODEL;
    const float* bias = (z == 0) ? biq : (z == 1) ? bik : biv;
    u16* C = (z == 0) ? oq : (z == 1) ? ok : ov;
    const float scale = (z == 0) ? sq : 1.0f;
    const int m0 = blockIdx.x * 128, n0 = blockIdx.y * 128;
    const int wm = (w >> 1) * 64, wn = (w & 1) * 64;

    // staging lane map: row-in-group = lane>>2 (16 rows/issue), slot = lane&3.
    const int srow = lane >> 2;
    const int sunit = (lane & 3) ^ (srow & 3);
    const u16* aBase = A + (size_t)(m0 + w * 32 + srow) * DMODEL + sunit * 8;
    const u16* bBase = B + (size_t)(n0 + w * 32 + srow) * DMODEL + sunit * 8;
    // read swizzle: slot = quad ^ (row&3); row = wm/wn + mt*16 + l16 -> l16&3
    const int un8 = (quad ^ (l16 & 3)) * 8;

    f32x4 acc[4][4] = {};

#define STAGE(AS_, BS_, kt_)                                                   \
    do {                                                                       \
        dma16(aBase + (kt_) * 32,                &AS_[(w * 32) * 32]);         \
        dma16(aBase + 16 * DMODEL + (kt_) * 32,  &AS_[(w * 32 + 16) * 32]);    \
        dma16(bBase + (kt_) * 32,                &BS_[(w * 32) * 32]);         \
        dma16(bBase + 16 * DMODEL + (kt_) * 32,  &BS_[(w * 32 + 16) * 32]);    \
    } while (0)

#define WAITC4 asm volatile("s_waitcnt vmcnt(4)" ::: "memory")
#define WAITC0 asm volatile("s_waitcnt vmcnt(0)" ::: "memory")
// barrier WITH compiler memory fence: no LDS/global op may cross it.
#define BAR()                                                                  \
    do {                                                                       \
        asm volatile("s_barrier" ::: "memory");                                \
        __builtin_amdgcn_sched_barrier(0);                                     \
    } while (0)

#define COMPUTE(AS_, BS_)                                                      \
    do {                                                                       \
        s16x8 af[4], bf[4];                                                    \
        _Pragma("unroll")                                                      \
        for (int mt = 0; mt < 4; ++mt) {                                       \
            af[mt] = *(const s16x8*)(&AS_[(wm + mt * 16 + l16) * 32 + un8]);   \
            bf[mt] = *(const s16x8*)(&BS_[(wn + mt * 16 + l16) * 32 + un8]);   \
        }                                                                      \
        _Pragma("unroll")                                                      \
        for (int mt = 0; mt < 4; ++mt) {                                       \
            _Pragma("unroll")                                                  \
            for (int nt = 0; nt < 4; ++nt)                                     \
                acc[mt][nt] = MFMA32K(af[mt], bf[nt], acc[mt][nt]);            \
        }                                                                      \
    } while (0)

    const int NT = DMODEL / 32;  // 32 tiles
    STAGE(As0, Bs0, 0);
    for (int tt = 0; tt < NT - 2; tt += 2) {
        STAGE(As1, Bs1, tt + 1);
        WAITC4; BAR();
        COMPUTE(As0, Bs0);
        BAR();
        STAGE(As0, Bs0, tt + 2);
        WAITC4; BAR();
        COMPUTE(As1, Bs1);
        BAR();
    }
    // peel: tiles NT-2, NT-1
    STAGE(As1, Bs1, NT - 1);
    WAITC4; BAR();
    COMPUTE(As0, Bs0);
    BAR();
    WAITC0; BAR();
    COMPUTE(As1, Bs1);

#undef STAGE
#undef WAITC4
#undef WAITC0
#undef BAR
#undef COMPUTE

#pragma unroll
    for (int mt = 0; mt < 4; ++mt)
#pragma unroll
        for (int nt = 0; nt < 4; ++nt) {
            int col = n0 + wn + nt * 16 + l16;
            float bv_ = bias[col];
#pragma unroll
            for (int r = 0; r < 4; ++r) {
                int row = m0 + wm + mt * 16 + quad * 4 + r;
                C[(size_t)row * DMODEL + col] = f2bf((acc[mt][nt][r] + bv_) * scale);
            }
        }
}

// ---------------------------------------------------------------------------
// Output projection GEMM: round-6 proven BK=64 2-barrier structure, fp32 out.
// Kept unchanged as the intra-run control for the gemm_qkv pipeline change.
// ---------------------------------------------------------------------------
__global__ __launch_bounds__(256) void gemm_o(const u16* __restrict__ A,
                                              const u16* __restrict__ Bt,
                                              const float* __restrict__ bias,
                                              float* __restrict__ Cp) {
    __shared__ u16 As[128 * 64];
    __shared__ u16 Bs[128 * 64];
    const int t = threadIdx.x;
    const int w = t >> 6, lane = t & 63, quad = lane >> 4, l16 = lane & 15;
    const int m0 = blockIdx.x * 128, n0 = blockIdx.y * 128;
    const int wm = (w >> 1) * 64, wn = (w & 1) * 64;
    const int lr8 = lane >> 3;
    const int lun = (lane & 7) ^ lr8;

    f32x4 acc[4][4] = {};

    for (int k0 = 0; k0 < DMODEL; k0 += 64) {
#pragma unroll
        for (int j = 0; j < 4; ++j) {
            int r8 = w * 32 + j * 8;
            dma16(A + (size_t)(m0 + r8 + lr8) * DMODEL + k0 + lun * 8, &As[r8 * 64]);
            dma16(Bt + (size_t)(n0 + r8 + lr8) * DMODEL + k0 + lun * 8, &Bs[r8 * 64]);
        }
        __syncthreads();
#pragma unroll
        for (int half = 0; half < 2; ++half) {
            s16x8 af[4], bf[4];
#pragma unroll
            for (int mt = 0; mt < 4; ++mt) {
                int un = ((half * 4 + quad) ^ (l16 & 7)) * 8;
                af[mt] = *(const s16x8*)(&As[(wm + mt * 16 + l16) * 64 + un]);
                bf[mt] = *(const s16x8*)(&Bs[(wn + mt * 16 + l16) * 64 + un]);
            }
#pragma unroll
            for (int mt = 0; mt < 4; ++mt)
#pragma unroll
                for (int nt = 0; nt < 4; ++nt)
                    acc[mt][nt] = MFMA32K(af[mt], bf[nt], acc[mt][nt]);
        }
        __syncthreads();
    }

#pragma unroll
    for (int mt = 0; mt < 4; ++mt)
#pragma unroll
        for (int nt = 0; nt < 4; ++nt) {
            int col = n0 + wn + nt * 16 + l16;
            float bv_ = bias[col];
#pragma unroll
            for (int r = 0; r < 4; ++r) {
                int row = m0 + wm + mt * 16 + quad * 4 + r;
                Cp[(size_t)row * DMODEL + col] = acc[mt][nt][r] + bv_;
            }
        }
}

// ---------------------------------------------------------------------------
// Flash attention, S^T formulation, fixed m=0. Grid (head, q-block, b),
// head-fast: all 8 q-blocks of one (b,h) KV stream land on the same XCD.
// v10 (measured 114.3-121.5us): QBLK=256 + ones-row lsum. Unchanged.
// ---------------------------------------------------------------------------
__global__ __launch_bounds__(256, 2) void attn3(const u16* __restrict__ qb,
                                                const u16* __restrict__ kb,
                                                const u16* __restrict__ vb,
                                                u16* __restrict__ ctxb) {
    __shared__ u16 Ks[64 * 64];  // [key][swizzled 16B units], stride 64
    __shared__ u16 Vt[80 * 72];  // [dim 0..63 + ones-row 64][swizzled key]
    const int t = threadIdx.x;
    const int w = t >> 6, lane = t & 63, quad = lane >> 4, l16 = lane & 15;
    const int h = blockIdx.x, b = blockIdx.z, q0 = blockIdx.y * 256;

    // Q B-fragments (pre-scaled by 0.125*log2e in projection epilogue)
    // wave w owns q-rows [q0 + w*64, q0 + w*64 + 64)
    s16x8 bq[4][2];
#pragma unroll
    for (int qs = 0; qs < 4; ++qs) {
        size_t base = (size_t)(b * SEQ + q0 + w * 64 + qs * 16 + l16) * DMODEL + h * HDIM + quad * 8;
        bq[qs][0] = *(const s16x8*)(qb + base);
        bq[qs][1] = *(const s16x8*)(qb + base + 32);
    }

    // ones-row block init (rows 64..79): row 64 = 1.0 bf16, rest 0. Once.
    for (int idx = t; idx < 16 * 72; idx += 256) {
        int r = idx / 72, c = idx - r * 72;
        Vt[(64 + r) * 72 + c] = (r == 0) ? (u16)0x3F80 : (u16)0;
    }

    const int krow = lane >> 3;
    const int kunit = (lane & 7) ^ (krow & 7);

    f32x4 o[4][5] = {};  // [qs][mt]; mt=4 is the P-sum row

    for (int s0 = 0; s0 < SEQ; s0 += 64) {
        __syncthreads();
        // ---- K via dma16 (swizzled): Ks[row][unit ^ (row&7)] ----
#pragma unroll
        for (int j = 0; j < 2; ++j) {
            int row = w * 16 + j * 8 + krow;
            dma16(kb + (size_t)(b * SEQ + s0 + row) * DMODEL + h * HDIM + kunit * 8,
                  &Ks[(w * 16 + j * 8) * 64]);
        }
        // ---- V transposed + swizzled (manual) ----
#pragma unroll
        for (int i = 0; i < 2; ++i) {
            int idx = i * 256 + t;
            int key = idx >> 3, seg = idx & 7;
            union { uint4 v; u16 s[8]; } u;
            u.v = *(const uint4*)(vb + (size_t)(b * SEQ + s0 + key) * DMODEL + h * HDIM + seg * 8);
            int col = (((key >> 3) ^ seg) << 3) + (key & 7);
#pragma unroll
            for (int ii = 0; ii < 8; ++ii)
                Vt[(seg * 8 + ii) * 72 + col] = u.s[ii];
        }
        __syncthreads();

        // ---- K A-fragments (swizzled units: 2-way, free) ----
        s16x8 ak[4][2];
#pragma unroll
        for (int kt = 0; kt < 4; ++kt) {
            int row = kt * 16 + l16;
#pragma unroll
            for (int hf = 0; hf < 2; ++hf) {
                int un = (hf * 4 + quad) ^ (l16 & 7);
                ak[kt][hf] = *(const s16x8*)(&Ks[row * 64 + un * 8]);
            }
        }

        // ---- scores + softmax (m=0 fixed), P packed in regs, 4 q-strips ----
        unsigned int pk[4][4][2];
#pragma unroll
        for (int qs = 0; qs < 4; ++qs) {
            f32x4 sc[4];
#pragma unroll
            for (int kt = 0; kt < 4; ++kt) {
                f32x4 zz = {0.0f, 0.0f, 0.0f, 0.0f};
                zz = MFMA32K(ak[kt][0], bq[qs][0], zz);
                sc[kt] = MFMA32K(ak[kt][1], bq[qs][1], zz);
            }
#pragma unroll
            for (int kt = 0; kt < 4; ++kt) {
                float p0 = __builtin_amdgcn_exp2f(sc[kt][0]);
                float p1 = __builtin_amdgcn_exp2f(sc[kt][1]);
                float p2 = __builtin_amdgcn_exp2f(sc[kt][2]);
                float p3 = __builtin_amdgcn_exp2f(sc[kt][3]);
                pk[qs][kt][0] = pack2bf(p0, p1);
                pk[qs][kt][1] = pack2bf(p2, p3);
            }
        }

        // ---- PV: O^T += V^T . P^T; mt=4 accumulates sum_k P (ones-row) ----
#pragma unroll
        for (int mt = 0; mt < 5; ++mt) {
            const int dim = mt * 16 + l16;
            const int swz = (dim >> 3) & 7;
            const int rowoff = dim * 72;
#pragma unroll
            for (int kt = 0; kt < 4; ++kt) {
                int col = ((((kt * 2) + (quad >> 1)) ^ swz) << 3) + ((quad & 1) << 2);
                s16x4 av = *(const s16x4*)(&Vt[rowoff + col]);
#pragma unroll
                for (int qs = 0; qs < 4; ++qs) {
                    union { unsigned int u[2]; s16x4 v; } pb;
                    pb.u[0] = pk[qs][kt][0];
                    pb.u[1] = pk[qs][kt][1];
                    o[qs][mt] = MFMA16K(av, pb.v, o[qs][mt]);
                }
            }
        }
    }

    // ---- epilogue: O^T[dim][qrow] / lsum -> ctx (bf16, dword stores) ----
    // lsum for q=l16 lives in o[qs][4][0] at quad-0 lanes; broadcast via shfl.
#pragma unroll
    for (int qs = 0; qs < 4; ++qs) {
        float ls = __shfl(o[qs][4][0], l16);
        float rl = 1.0f / ls;
        size_t rowbase = (size_t)(b * SEQ + q0 + w * 64 + qs * 16 + l16) * DMODEL + h * HDIM;
#pragma unroll
        for (int mt = 0; mt < 4; ++mt)
#pragma unroll
            for (int rr = 0; rr < 2; ++rr) {
                unsigned int v = pack2bf(o[qs][mt][rr * 2] * rl, o[qs][mt][rr * 2 + 1] * rl);
                *(unsigned int*)(&ctxb[rowbase + mt * 16 + quad * 4 + rr * 2]) = v;
            }
    }
}

// ---------------------------------------------------------------------------
extern "C" void kernel_launch(void* const* d_in, const int* in_sizes, int n_in,
                              void* d_out, int out_size, void* d_ws, size_t ws_size,
                              hipStream_t stream) {
    const float* queries = (const float*)d_in[0];
    const float* keys    = (const float*)d_in[1];
    const float* values  = (const float*)d_in[2];
    const float* Wq = (const float*)d_in[3];
    const float* bq = (const float*)d_in[4];
    const float* Wk = (const float*)d_in[5];
    const float* bk = (const float*)d_in[6];
    const float* Wv = (const float*)d_in[7];
    const float* bv = (const float*)d_in[8];
    const float* Wo = (const float*)d_in[9];
    const float* bo = (const float*)d_in[10];
    float* out = (float*)d_out;

    // workspace layout (104 MB total)
    char* ws = (char*)d_ws;
    u16* Wt   = (u16*)ws;                           // 8 MB  (4 x 1024^2 bf16)
    u16* aq   = (u16*)(ws + ((size_t)8 << 20));     // 16 MB bf16 queries
    u16* ak   = (u16*)(ws + ((size_t)24 << 20));    // 16 MB bf16 keys
    u16* av   = (u16*)(ws + ((size_t)40 << 20));    // 16 MB bf16 values
    u16* qbuf = (u16*)(ws + ((size_t)56 << 20));    // 16 MB
    u16* kbuf = (u16*)(ws + ((size_t)72 << 20));    // 16 MB
    u16* vbuf = (u16*)(ws + ((size_t)88 << 20));    // 16 MB
    u16* ctxb = qbuf;  // alias: attn block rewrites only the rows it read

    const size_t WSZ = (size_t)DMODEL * DMODEL;
    const float S2 = 0.125f * 1.44269504088896340736f;  // 1/sqrt(64) * log2(e)

    dim3 blk(256);

    prep<<<dim3(13312), blk, 0, stream>>>(queries, keys, values, aq, ak, av,
                                          Wq, Wk, Wv, Wo, Wt);

    gemm_qkv<<<dim3(64, 8, 3), blk, 0, stream>>>(aq, ak, av, Wt,
                                                 bq, bk, bv, qbuf, kbuf, vbuf, S2);

    attn3<<<dim3(NHEADS, SEQ / 256, BATCH), blk, 0, stream>>>(qbuf, kbuf, vbuf, ctxb);

    gemm_o<<<dim3(64, 8), blk, 0, stream>>>(ctxb, Wt + 3 * WSZ, bo, out);
}